// Round 6
// baseline (63.350 us; speedup 1.0000x reference)
//
#include <hip/hip_runtime.h>

#define NUM_EXPERTS 64
#define CAPACITY    320
#define NUM_TOKENS  16384
#define EMBED_DIM   2048
#define SUB         64                        // subchunk = 64 tokens = 1 wave
#define NUM_SUB     (NUM_TOKENS / SUB)        // 256
#define NUM_SLOTS   (NUM_EXPERTS * CAPACITY)  // 20480
#define NUM_ITEMS   (NUM_TOKENS + NUM_SLOTS)  // 36864

typedef float f32x4 __attribute__((ext_vector_type(4)));

// ws layout (ints): offsets[NUM_SUB][NUM_EXPERTS] (64 KB) | totals[NUM_EXPERTS]

// Single block: per-subchunk histogram (LDS atomics, 64 KB) -> in-place
// per-expert exclusive scan over 256 subchunks -> offsets, totals, dropped.
__global__ __launch_bounds__(1024)
void k_prelude(const int* __restrict__ ids,
               int* __restrict__ offsets,
               int* __restrict__ totals,
               float* __restrict__ out_dropped) {
    __shared__ int cnt[NUM_SUB * NUM_EXPERTS];   // exactly 64 KB
    int t = threadIdx.x;                         // 1024 threads
    for (int i = t; i < NUM_SUB * NUM_EXPERTS; i += 1024) cnt[i] = 0;
    __syncthreads();
    #pragma unroll
    for (int r = 0; r < NUM_TOKENS / 1024; ++r) {
        int idx = r * 1024 + t;
        atomicAdd(&cnt[(idx >> 6) * NUM_EXPERTS + ids[idx]], 1);
    }
    __syncthreads();
    if (t < NUM_EXPERTS) {
        int run = 0;
        for (int s = 0; s < NUM_SUB; ++s) {      // thread e: lanes hit
            int c = cnt[s * NUM_EXPERTS + t];    // consecutive banks
            cnt[s * NUM_EXPERTS + t] = run;      // exclusive prefix in place
            run += c;
        }
        totals[t] = run;
        int dropped = run > CAPACITY ? run - CAPACITY : 0;
        #pragma unroll
        for (int off = 32; off > 0; off >>= 1)
            dropped += __shfl_down(dropped, off);
        if (t == 0) out_dropped[0] = (float)dropped;
    }
    __syncthreads();
    for (int i = t; i < NUM_SUB * NUM_EXPERTS; i += 1024) offsets[i] = cnt[i];
}

// 4 independent waves per block, one item per wave. No LDS, no barriers.
// Items [0, NUM_TOKENS): token copy — rank via in-wave ballot over the
//   token's 64-id subchunk; sequential row reads, scattered row writes.
// Items [NUM_TOKENS, NUM_ITEMS): slot zero-fill, early-exit when filled.
__global__ __launch_bounds__(256)
void k_dispatch(const float* __restrict__ x,
                const int* __restrict__ ids,
                const float* __restrict__ weights,
                const int* __restrict__ offsets,
                const int* __restrict__ totals,
                float* __restrict__ out_x,
                float* __restrict__ out_combine,
                float* __restrict__ out_tokidx) {
    int item = blockIdx.x * 4 + (threadIdx.x >> 6);
    int l    = threadIdx.x & 63;
    if (item < NUM_TOKENS) {
        int tok = item;
        const f32x4* src = (const f32x4*)(x + (size_t)tok * EMBED_DIM);
        f32x4 v0 = src[l];           // issue all row loads first; id fetch
        f32x4 v1 = src[l +  64];     // + ballot latency hides under them
        f32x4 v2 = src[l + 128];
        f32x4 v3 = src[l + 192];
        f32x4 v4 = src[l + 256];
        f32x4 v5 = src[l + 320];
        f32x4 v6 = src[l + 384];
        f32x4 v7 = src[l + 448];
        int sub = tok >> 6, tp = tok & 63;
        int myid = ids[sub * SUB + l];
        int e = __shfl(myid, tp);
        unsigned long long m = __ballot((l < tp) && (myid == e));
        int pos = offsets[sub * NUM_EXPERTS + e] + __popcll(m);
        if (pos >= CAPACITY) return;             // dropped (wave-uniform)
        size_t slot = (size_t)e * CAPACITY + pos;
        f32x4* dst = (f32x4*)(out_x + slot * EMBED_DIM);
        dst[l]       = v0;
        dst[l +  64] = v1;
        dst[l + 128] = v2;
        dst[l + 192] = v3;
        dst[l + 256] = v4;
        dst[l + 320] = v5;
        dst[l + 384] = v6;
        dst[l + 448] = v7;
        if (l == 0) {
            out_combine[slot] = weights[tok];
            out_tokidx[slot]  = (float)tok;
        }
    } else {
        int s   = item - NUM_TOKENS;
        int e   = s / CAPACITY;
        int pos = s - e * CAPACITY;
        if (pos < totals[e]) return;             // filled by a token wave
        f32x4* dst = (f32x4*)(out_x + (size_t)s * EMBED_DIM);
        f32x4 z = {0.f, 0.f, 0.f, 0.f};
        dst[l]       = z;
        dst[l +  64] = z;
        dst[l + 128] = z;
        dst[l + 192] = z;
        dst[l + 256] = z;
        dst[l + 320] = z;
        dst[l + 384] = z;
        dst[l + 448] = z;
        if (l == 0) {
            out_combine[s] = 0.0f;
            out_tokidx[s]  = -1.0f;
        }
    }
}

extern "C" void kernel_launch(void* const* d_in, const int* in_sizes, int n_in,
                              void* d_out, int out_size, void* d_ws, size_t ws_size,
                              hipStream_t stream) {
    const float* x          = (const float*)d_in[0];
    const int*   expert_ids = (const int*)d_in[1];
    const float* weights    = (const float*)d_in[2];

    float* out         = (float*)d_out;
    float* out_x       = out;
    float* out_combine = out + (size_t)NUM_SLOTS * EMBED_DIM;
    float* out_tokidx  = out_combine + NUM_SLOTS;
    float* out_dropped = out_tokidx  + NUM_SLOTS;

    int* offsets = (int*)d_ws;
    int* totals  = offsets + NUM_SUB * NUM_EXPERTS;

    k_prelude<<<1, 1024, 0, stream>>>(expert_ids, offsets, totals, out_dropped);
    k_dispatch<<<NUM_ITEMS / 4, 256, 0, stream>>>(
        x, expert_ids, weights, offsets, totals,
        out_x, out_combine, out_tokidx);
}

// Round 7
// 63.163 us; speedup vs baseline: 1.0030x; 1.0030x over previous
//
#include <hip/hip_runtime.h>

#define NUM_EXPERTS 64
#define CAPACITY    320
#define NUM_TOKENS  16384
#define EMBED_DIM   2048
#define SUB         64                        // subchunk = 64 tokens = 1 wave
#define NUM_SUB     (NUM_TOKENS / SUB)        // 256
#define NUM_SLOTS   (NUM_EXPERTS * CAPACITY)  // 20480
#define NUM_ITEMS   (NUM_TOKENS + NUM_SLOTS)  // 36864

typedef float f32x4 __attribute__((ext_vector_type(4)));

// ws layout (ints): offsets[NUM_SUB][NUM_EXPERTS] (64 KB) | totals[NUM_EXPERTS]

// Single block: per-subchunk histogram (LDS atomics, 64 KB) -> in-place
// per-expert exclusive scan over 256 subchunks -> offsets, totals, dropped.
__global__ __launch_bounds__(1024)
void k_prelude(const int* __restrict__ ids,
               int* __restrict__ offsets,
               int* __restrict__ totals,
               float* __restrict__ out_dropped) {
    __shared__ int cnt[NUM_SUB * NUM_EXPERTS];   // exactly 64 KB
    int t = threadIdx.x;                         // 1024 threads
    for (int i = t; i < NUM_SUB * NUM_EXPERTS; i += 1024) cnt[i] = 0;
    __syncthreads();
    #pragma unroll
    for (int r = 0; r < NUM_TOKENS / 1024; ++r) {
        int idx = r * 1024 + t;
        atomicAdd(&cnt[(idx >> 6) * NUM_EXPERTS + ids[idx]], 1);
    }
    __syncthreads();
    if (t < NUM_EXPERTS) {
        int run = 0;
        for (int s = 0; s < NUM_SUB; ++s) {
            int c = cnt[s * NUM_EXPERTS + t];
            cnt[s * NUM_EXPERTS + t] = run;      // exclusive prefix in place
            run += c;
        }
        totals[t] = run;
        int dropped = run > CAPACITY ? run - CAPACITY : 0;
        #pragma unroll
        for (int off = 32; off > 0; off >>= 1)
            dropped += __shfl_down(dropped, off);
        if (t == 0) out_dropped[0] = (float)dropped;
    }
    __syncthreads();
    for (int i = t; i < NUM_SUB * NUM_EXPERTS; i += 1024) offsets[i] = cnt[i];
}

// 4 independent waves per block, one item per wave. No LDS, no barriers.
// CRITICAL load order: ids + all-expert offsets + weight FIRST, then the 8
// row loads — the ballot then waits only on the oldest loads (vmcnt keeps
// the row loads in flight), and stores drain the rows progressively.
__global__ __launch_bounds__(256)
void k_dispatch(const float* __restrict__ x,
                const int* __restrict__ ids,
                const float* __restrict__ weights,
                const int* __restrict__ offsets,
                const int* __restrict__ totals,
                float* __restrict__ out_x,
                float* __restrict__ out_combine,
                float* __restrict__ out_tokidx) {
    int item = blockIdx.x * 4 + (threadIdx.x >> 6);
    int l    = threadIdx.x & 63;
    if (item < NUM_TOKENS) {
        int tok = item;
        int sub = tok >> 6, tp = tok & 63;
        int   myid = ids[sub * SUB + l];             // oldest outstanding
        int   offl = offsets[sub * NUM_EXPERTS + l]; // all 64 experts' offsets
        float w    = weights[tok];                   // wave-uniform
        const f32x4* src = (const f32x4*)(x + (size_t)tok * EMBED_DIM);
        f32x4 v0 = src[l];
        f32x4 v1 = src[l +  64];
        f32x4 v2 = src[l + 128];
        f32x4 v3 = src[l + 192];
        f32x4 v4 = src[l + 256];
        f32x4 v5 = src[l + 320];
        f32x4 v6 = src[l + 384];
        f32x4 v7 = src[l + 448];
        int e = __shfl(myid, tp);                    // waits ids only
        unsigned long long m = __ballot((l < tp) && (myid == e));
        int pos = __shfl(offl, e) + __popcll(m);     // waits offl only
        if (pos >= CAPACITY) return;                 // dropped (wave-uniform)
        size_t slot = (size_t)e * CAPACITY + pos;
        f32x4* dst = (f32x4*)(out_x + slot * EMBED_DIM);
        dst[l]       = v0;                           // progressive vmcnt drain
        dst[l +  64] = v1;
        dst[l + 128] = v2;
        dst[l + 192] = v3;
        dst[l + 256] = v4;
        dst[l + 320] = v5;
        dst[l + 384] = v6;
        dst[l + 448] = v7;
        if (l == 0) {
            out_combine[slot] = w;
            out_tokidx[slot]  = (float)tok;
        }
    } else {
        int s   = item - NUM_TOKENS;
        int e   = s / CAPACITY;
        int pos = s - e * CAPACITY;
        if (pos < totals[e]) return;                 // filled by a token wave
        f32x4* dst = (f32x4*)(out_x + (size_t)s * EMBED_DIM);
        f32x4 z = {0.f, 0.f, 0.f, 0.f};
        dst[l]       = z;
        dst[l +  64] = z;
        dst[l + 128] = z;
        dst[l + 192] = z;
        dst[l + 256] = z;
        dst[l + 320] = z;
        dst[l + 384] = z;
        dst[l + 448] = z;
        if (l == 0) {
            out_combine[s] = 0.0f;
            out_tokidx[s]  = -1.0f;
        }
    }
}

extern "C" void kernel_launch(void* const* d_in, const int* in_sizes, int n_in,
                              void* d_out, int out_size, void* d_ws, size_t ws_size,
                              hipStream_t stream) {
    const float* x          = (const float*)d_in[0];
    const int*   expert_ids = (const int*)d_in[1];
    const float* weights    = (const float*)d_in[2];

    float* out         = (float*)d_out;
    float* out_x       = out;
    float* out_combine = out + (size_t)NUM_SLOTS * EMBED_DIM;
    float* out_tokidx  = out_combine + NUM_SLOTS;
    float* out_dropped = out_tokidx  + NUM_SLOTS;

    int* offsets = (int*)d_ws;
    int* totals  = offsets + NUM_SUB * NUM_EXPERTS;

    k_prelude<<<1, 1024, 0, stream>>>(expert_ids, offsets, totals, out_dropped);
    k_dispatch<<<NUM_ITEMS / 4, 256, 0, stream>>>(
        x, expert_ids, weights, offsets, totals,
        out_x, out_combine, out_tokidx);
}

// Round 8
// 57.708 us; speedup vs baseline: 1.0978x; 1.0945x over previous
//
#include <hip/hip_runtime.h>

#define NUM_EXPERTS 64
#define CAPACITY    320
#define NUM_TOKENS  16384
#define EMBED_DIM   2048
#define SUB         64                        // subchunk = 64 tokens
#define NUM_SUB     (NUM_TOKENS / SUB)        // 256
#define NUM_SLOTS   (NUM_EXPERTS * CAPACITY)  // 20480
#define NUM_ITEMS   (NUM_TOKENS + NUM_SLOTS)  // 36864

typedef float f32x4 __attribute__((ext_vector_type(4)));
typedef int   i32x4 __attribute__((ext_vector_type(4)));

// ws layout (ints):
//   offsets[NUM_SUB][NUM_EXPERTS]  (64 KB)  exclusive per-expert prefix
//   totals[NUM_EXPERTS]
//   overflow[NUM_EXPERTS]

// 64 blocks, one per expert e. Thread t counts expert-e tokens in subchunk t
// (64 ids via int4 loads), then a 256-wide LDS scan gives exclusive offsets.
// Fully parallel across 64 CUs — replaces the serial single-block prelude.
__global__ __launch_bounds__(256)
void k_prelude(const int* __restrict__ ids,
               int* __restrict__ offsets,
               int* __restrict__ totals,
               int* __restrict__ overflow) {
    int e = blockIdx.x, t = threadIdx.x;
    const i32x4* ids4 = (const i32x4*)(ids + t * SUB);
    int cnt = 0;
    #pragma unroll
    for (int i = 0; i < SUB / 4; ++i) {
        i32x4 v = ids4[i];
        cnt += (v.x == e) + (v.y == e) + (v.z == e) + (v.w == e);
    }
    __shared__ int s[NUM_SUB];
    s[t] = cnt;
    __syncthreads();
    #pragma unroll
    for (int off = 1; off < NUM_SUB; off <<= 1) {
        int v = (t >= off) ? s[t - off] : 0;
        __syncthreads();
        s[t] += v;
        __syncthreads();
    }
    offsets[t * NUM_EXPERTS + e] = s[t] - cnt;   // exclusive prefix
    if (t == NUM_SUB - 1) {
        totals[e]   = s[t];
        overflow[e] = s[t] > CAPACITY ? s[t] - CAPACITY : 0;
    }
}

// Block-per-item copy (R5's proven granularity) with barrier-free in-wave
// rank: each of the 4 waves redundantly computes the token's (e,pos) from
// the 64-id subchunk (coalesced 256B, L1-hot) — no LDS, no __syncthreads.
// Small loads issue before the row loads so the ballot's waitcnt leaves the
// row loads in flight.
__global__ __launch_bounds__(256)
void k_dispatch(const float* __restrict__ x,
                const int* __restrict__ ids,
                const float* __restrict__ weights,
                const int* __restrict__ offsets,
                const int* __restrict__ totals,
                const int* __restrict__ overflow,
                float* __restrict__ out_x,
                float* __restrict__ out_combine,
                float* __restrict__ out_tokidx,
                float* __restrict__ out_dropped) {
    int bid = blockIdx.x;
    int t   = threadIdx.x;
    int l   = t & 63;
    if (bid < NUM_TOKENS) {
        int tok = bid, sub = tok >> 6, tp = tok & 63;
        int   myid = ids[sub * SUB + l];              // oldest outstanding
        int   offl = offsets[sub * NUM_EXPERTS + l];  // all experts' offsets
        float w    = weights[tok];
        const f32x4* src = (const f32x4*)(x + (size_t)tok * EMBED_DIM);
        f32x4 a = src[t];                             // rows stay in flight
        f32x4 b = src[t + 256];
        int e = __shfl(myid, tp);
        unsigned long long m = __ballot((l < tp) && (myid == e));
        int pos = __shfl(offl, e) + __popcll(m);      // wave-uniform
        if (pos >= CAPACITY) return;                  // dropped token
        size_t slot = (size_t)e * CAPACITY + pos;
        f32x4* dst = (f32x4*)(out_x + slot * EMBED_DIM);
        dst[t]       = a;
        dst[t + 256] = b;
        if (t == 0) {
            out_combine[slot] = w;
            out_tokidx[slot]  = (float)tok;
        }
    } else if (bid < NUM_ITEMS) {
        int s   = bid - NUM_TOKENS;
        int e   = s / CAPACITY;
        int pos = s - e * CAPACITY;
        if (pos < totals[e]) return;                  // filled by a token block
        f32x4* dst = (f32x4*)(out_x + (size_t)s * EMBED_DIM);
        f32x4 z = {0.f, 0.f, 0.f, 0.f};
        dst[t]       = z;
        dst[t + 256] = z;
        if (t == 0) {
            out_combine[s] = 0.0f;
            out_tokidx[s]  = -1.0f;
        }
    } else {
        // tail block: tokens_dropped = sum(overflow)
        if (t < 64) {
            int v = overflow[t];
            #pragma unroll
            for (int off = 32; off > 0; off >>= 1)
                v += __shfl_down(v, off);
            if (t == 0) out_dropped[0] = (float)v;
        }
    }
}

extern "C" void kernel_launch(void* const* d_in, const int* in_sizes, int n_in,
                              void* d_out, int out_size, void* d_ws, size_t ws_size,
                              hipStream_t stream) {
    const float* x          = (const float*)d_in[0];
    const int*   expert_ids = (const int*)d_in[1];
    const float* weights    = (const float*)d_in[2];

    float* out         = (float*)d_out;
    float* out_x       = out;
    float* out_combine = out + (size_t)NUM_SLOTS * EMBED_DIM;
    float* out_tokidx  = out_combine + NUM_SLOTS;
    float* out_dropped = out_tokidx  + NUM_SLOTS;

    int* offsets  = (int*)d_ws;
    int* totals   = offsets + NUM_SUB * NUM_EXPERTS;
    int* overflow = totals  + NUM_EXPERTS;

    k_prelude<<<NUM_EXPERTS, 256, 0, stream>>>(expert_ids, offsets, totals, overflow);
    k_dispatch<<<NUM_ITEMS + 1, 256, 0, stream>>>(
        x, expert_ids, weights, offsets, totals, overflow,
        out_x, out_combine, out_tokidx, out_dropped);
}

// Round 9
// 52.733 us; speedup vs baseline: 1.2013x; 1.0943x over previous
//
#include <hip/hip_runtime.h>

#define NUM_EXPERTS 64
#define CAPACITY    320
#define NUM_TOKENS  16384
#define EMBED_DIM   2048
#define SUB         64                        // subchunk = 64 tokens
#define NUM_SUB     (NUM_TOKENS / SUB)        // 256
#define NUM_SLOTS   (NUM_EXPERTS * CAPACITY)  // 20480
#define NUM_ITEMS   (NUM_TOKENS + NUM_SLOTS)  // 36864

typedef float f32x4 __attribute__((ext_vector_type(4)));
typedef int   i32x4 __attribute__((ext_vector_type(4)));

// ws layout (ints):
//   offsets[NUM_SUB][NUM_EXPERTS]  (64 KB)  exclusive per-expert prefix
//   totals[NUM_EXPERTS]
//   overflow[NUM_EXPERTS]

// 64 blocks, one per expert e. Thread t counts expert-e tokens in subchunk t
// (64 ids via int4 loads), then a 256-wide LDS scan gives exclusive offsets.
__global__ __launch_bounds__(256)
void k_prelude(const int* __restrict__ ids,
               int* __restrict__ offsets,
               int* __restrict__ totals,
               int* __restrict__ overflow) {
    int e = blockIdx.x, t = threadIdx.x;
    const i32x4* ids4 = (const i32x4*)(ids + t * SUB);
    int cnt = 0;
    #pragma unroll
    for (int i = 0; i < SUB / 4; ++i) {
        i32x4 v = ids4[i];
        cnt += (v.x == e) + (v.y == e) + (v.z == e) + (v.w == e);
    }
    __shared__ int s[NUM_SUB];
    s[t] = cnt;
    __syncthreads();
    #pragma unroll
    for (int off = 1; off < NUM_SUB; off <<= 1) {
        int v = (t >= off) ? s[t - off] : 0;
        __syncthreads();
        s[t] += v;
        __syncthreads();
    }
    offsets[t * NUM_EXPERTS + e] = s[t] - cnt;   // exclusive prefix
    if (t == NUM_SUB - 1) {
        totals[e]   = s[t];
        overflow[e] = s[t] > CAPACITY ? s[t] - CAPACITY : 0;
    }
}

// Block-per-item copy, barrier-free in-wave rank (R8 structure).
// CHANGE vs R8: the 8 KB row stores are NONTEMPORAL (evict-first) — the
// output is never re-read, so don't let 168 MB of stores evict the L3-
// resident x (134 MB) between graph replays. Loads stay plain (L3 hits).
__global__ __launch_bounds__(256)
void k_dispatch(const float* __restrict__ x,
                const int* __restrict__ ids,
                const float* __restrict__ weights,
                const int* __restrict__ offsets,
                const int* __restrict__ totals,
                const int* __restrict__ overflow,
                float* __restrict__ out_x,
                float* __restrict__ out_combine,
                float* __restrict__ out_tokidx,
                float* __restrict__ out_dropped) {
    int bid = blockIdx.x;
    int t   = threadIdx.x;
    int l   = t & 63;
    if (bid < NUM_TOKENS) {
        int tok = bid, sub = tok >> 6, tp = tok & 63;
        int   myid = ids[sub * SUB + l];              // oldest outstanding
        int   offl = offsets[sub * NUM_EXPERTS + l];  // all experts' offsets
        float w    = weights[tok];
        const f32x4* src = (const f32x4*)(x + (size_t)tok * EMBED_DIM);
        f32x4 a = src[t];                             // rows stay in flight
        f32x4 b = src[t + 256];
        int e = __shfl(myid, tp);
        unsigned long long m = __ballot((l < tp) && (myid == e));
        int pos = __shfl(offl, e) + __popcll(m);      // wave-uniform
        if (pos >= CAPACITY) return;                  // dropped token
        size_t slot = (size_t)e * CAPACITY + pos;
        f32x4* dst = (f32x4*)(out_x + slot * EMBED_DIM);
        __builtin_nontemporal_store(a, dst + t);
        __builtin_nontemporal_store(b, dst + t + 256);
        if (t == 0) {
            out_combine[slot] = w;
            out_tokidx[slot]  = (float)tok;
        }
    } else if (bid < NUM_ITEMS) {
        int s   = bid - NUM_TOKENS;
        int e   = s / CAPACITY;
        int pos = s - e * CAPACITY;
        if (pos < totals[e]) return;                  // filled by a token block
        f32x4* dst = (f32x4*)(out_x + (size_t)s * EMBED_DIM);
        f32x4 z = {0.f, 0.f, 0.f, 0.f};
        __builtin_nontemporal_store(z, dst + t);
        __builtin_nontemporal_store(z, dst + t + 256);
        if (t == 0) {
            out_combine[s] = 0.0f;
            out_tokidx[s]  = -1.0f;
        }
    } else {
        // tail block: tokens_dropped = sum(overflow)
        if (t < 64) {
            int v = overflow[t];
            #pragma unroll
            for (int off = 32; off > 0; off >>= 1)
                v += __shfl_down(v, off);
            if (t == 0) out_dropped[0] = (float)v;
        }
    }
}

extern "C" void kernel_launch(void* const* d_in, const int* in_sizes, int n_in,
                              void* d_out, int out_size, void* d_ws, size_t ws_size,
                              hipStream_t stream) {
    const float* x          = (const float*)d_in[0];
    const int*   expert_ids = (const int*)d_in[1];
    const float* weights    = (const float*)d_in[2];

    float* out         = (float*)d_out;
    float* out_x       = out;
    float* out_combine = out + (size_t)NUM_SLOTS * EMBED_DIM;
    float* out_tokidx  = out_combine + NUM_SLOTS;
    float* out_dropped = out_tokidx  + NUM_SLOTS;

    int* offsets  = (int*)d_ws;
    int* totals   = offsets + NUM_SUB * NUM_EXPERTS;
    int* overflow = totals  + NUM_EXPERTS;

    k_prelude<<<NUM_EXPERTS, 256, 0, stream>>>(expert_ids, offsets, totals, overflow);
    k_dispatch<<<NUM_ITEMS + 1, 256, 0, stream>>>(
        x, expert_ids, weights, offsets, totals, overflow,
        out_x, out_combine, out_tokidx, out_dropped);
}